// Round 7
// baseline (207.933 us; speedup 1.0000x reference)
//
#include <hip/hip_runtime.h>

// Particles2Grid: SPH cubic-spline splat, B=2, N=100000, C=4, grid 128^3.
// R4 scatter-atomics: 1403us (843MB of 32B atomic txns). R5 bin+gather: 240us.
// R6 8-cells/thread gather: 177us, gather 84us VALU-bound (VALUBusy 92%),
// bottleneck = per-column wave max-trip divergence + 5 prep dispatches.
// R7: flattened candidate cursor (one max-trip over lane totals), fused
// single-kernel scan (arrival-order chunk bases + within-column end compute),
// hipMemsetAsync for count zeroing.

constexpr int GX = 128, GY = 128, GZ = 128;
constexpr int NC = GX * GY * GZ;            // 2^21
constexpr int BD = 64;                       // bins per dim (2 cells/bin)
constexpr int NBIN = BD * BD * BD;           // 262144 per batch
constexpr int NB_TOT = 2 * NBIN;             // 524288 (B = 2)
constexpr float STEP   = 0.1f;
constexpr float INV_H  = 5.0f;               // 1 / 0.2
constexpr float H2     = 0.04f;              // 0.2^2
constexpr float SIGMA  = 318.30988618379067f; // 8 / (pi h^3)

// ---------------- fallback path (proven correct in R4) ----------------
__global__ __launch_bounds__(256) void zero_kernel(float4* __restrict__ out, int n4) {
  int stride = gridDim.x * blockDim.x;
  for (int i = blockIdx.x * blockDim.x + threadIdx.x; i < n4; i += stride)
    out[i] = make_float4(0.f, 0.f, 0.f, 0.f);
}

__global__ __launch_bounds__(256) void splat_kernel(
    const float4* __restrict__ locs, const float4* __restrict__ data,
    const float* __restrict__ density, float* __restrict__ out,
    int nTotal, int nPart) {
  int pid = blockIdx.x * blockDim.x + threadIdx.x;
  if (pid >= nTotal) return;
  int ox = blockIdx.y;
  float4 loc = locs[pid];
  float scale = 1.0f / (loc.w * density[pid]);
  int bx = (int)floorf(loc.x / STEP);
  int by = (int)floorf(loc.y / STEP);
  int bz = (int)floorf(loc.z / STEP);
  int cx = bx + ox - 2;
  if ((unsigned)cx >= (unsigned)GX) return;
  float dx = ((float)cx + 0.5f) * STEP - loc.x;
  float dx2 = dx * dx;
  if (dx2 >= H2) return;
  float4 dat = data[pid];
  int b = (pid >= nPart) ? 1 : 0;
  float* outb = out + (size_t)b * NC * 4;
  for (int oy = 0; oy < 5; ++oy) {
    int cy = by + oy - 2;
    if ((unsigned)cy >= (unsigned)GY) continue;
    float dy = ((float)cy + 0.5f) * STEP - loc.y;
    float dxy2 = dx2 + dy * dy;
    if (dxy2 >= H2) continue;
    float* rowp = outb + (size_t)((cx * GY + cy) * GZ) * 4;
    for (int oz = 0; oz < 5; ++oz) {
      int cz = bz + oz - 2;
      if ((unsigned)cz >= (unsigned)GZ) continue;
      float dz = ((float)cz + 0.5f) * STEP - loc.z;
      float d2 = dxy2 + dz * dz;
      if (d2 >= H2) continue;
      float q = sqrtf(d2) * INV_H;
      float w = (q < 0.5f) ? (1.0f + 6.0f * q * q * (q - 1.0f))
                           : (2.0f * (1.0f - q) * (1.0f - q) * (1.0f - q));
      float coef = SIGMA * scale * w;
      float* cellp = rowp + cz * 4;
      unsafeAtomicAdd(cellp + 0, coef * dat.x);
      unsafeAtomicAdd(cellp + 1, coef * dat.y);
      unsafeAtomicAdd(cellp + 2, coef * dat.z);
      unsafeAtomicAdd(cellp + 3, coef * dat.w);
    }
  }
}

// ---------------- binning + gather path ----------------

__device__ __forceinline__ int particle_bin(float4 l, int isB1) {
  int bx = (int)floorf(l.x / STEP);
  int by = (int)floorf(l.y / STEP);
  int bz = (int)floorf(l.z / STEP);
  bx = min(max(bx, 0), GX - 1) >> 1;
  by = min(max(by, 0), GY - 1) >> 1;
  bz = min(max(bz, 0), GZ - 1) >> 1;
  return (isB1 ? NBIN : 0) + ((bx * BD) + by) * BD + bz;
}

__global__ __launch_bounds__(256) void count_kernel(
    const float4* __restrict__ locs, int* __restrict__ counts,
    int nTotal, int nPart) {
  int pid = blockIdx.x * blockDim.x + threadIdx.x;
  if (pid >= nTotal) return;
  int bin = particle_bin(locs[pid], pid >= nPart);
  atomicAdd(counts + bin, 1);
}

// Fused scan: per-block (1024-bin chunk) exclusive scan; chunk base reserved
// via atomicAdd on a global cursor (arrival order). Cross-chunk order is
// arbitrary, but gather only ever needs within-COLUMN contiguity (columns are
// 64-bin aligned, chunks are 16 whole columns), and computes each window end
// as starts[last] + counts[last] — never reads across a chunk boundary.
__global__ __launch_bounds__(256) void scan_fused(
    const int* __restrict__ counts, int* __restrict__ starts,
    int* __restrict__ cursor, int* __restrict__ totalCursor) {
  __shared__ int sh[256];
  __shared__ int chunkBaseSh;
  int t = threadIdx.x, bid = blockIdx.x;
  int base = bid * 1024 + t * 4;
  int4 c = *reinterpret_cast<const int4*>(counts + base);
  int s = c.x + c.y + c.z + c.w;
  sh[t] = s;
  __syncthreads();
  for (int off = 1; off < 256; off <<= 1) {
    int x = (t >= off) ? sh[t - off] : 0;
    __syncthreads();
    sh[t] += x;
    __syncthreads();
  }
  int incl = sh[t];
  if (t == 255) chunkBaseSh = atomicAdd(totalCursor, incl);
  __syncthreads();
  int run = chunkBaseSh + incl - s;        // exclusive within chunk + base
  int4 o;
  o.x = run; run += c.x;
  o.y = run; run += c.y;
  o.z = run; run += c.z;
  o.w = run;
  *reinterpret_cast<int4*>(starts + base) = o;
  *reinterpret_cast<int4*>(cursor + base) = o;
}

__global__ __launch_bounds__(256) void scatter_kernel(
    const float4* __restrict__ locs, const float4* __restrict__ data,
    const float* __restrict__ density, int* __restrict__ cursor,
    float4* __restrict__ sA, float4* __restrict__ sB,
    int nTotal, int nPart) {
  int pid = blockIdx.x * blockDim.x + threadIdx.x;
  if (pid >= nTotal) return;
  float4 l = locs[pid];
  float4 d = data[pid];
  float s = SIGMA / (l.w * density[pid]);
  int bin = particle_bin(l, pid >= nPart);
  int idx = atomicAdd(cursor + bin, 1);
  sA[idx] = make_float4(l.x, l.y, l.z, s * d.x);
  sB[idx] = make_float4(s * d.y, s * d.z, s * d.w, 0.f);
}

// gather8f: one thread per 2x2x2 cell block; FLATTENED candidate loop.
// Each lane advances a single (col, p, e) cursor over its 9 bin-columns
// (ranges loaded on demand -> no runtime-indexed arrays). The wave pays one
// max over lane TOTALS (~20 trips) instead of 9 per-column maxes (~33-45).
__global__ __launch_bounds__(128) void gather8f_kernel(
    const int* __restrict__ starts, const int* __restrict__ counts,
    const float4* __restrict__ sA, const float4* __restrict__ sB,
    float4* __restrict__ out) {
  int tid = blockIdx.x * blockDim.x + threadIdx.x;   // 2 * 64^3 threads
  int b   = tid >> 18;
  int blk = tid & ((1 << 18) - 1);
  int Bz = blk & 63;
  int By = (blk >> 6) & 63;
  int Bx = blk >> 12;

  int cx0 = Bx << 1, cy0 = By << 1, cz0 = Bz << 1;
  float px0 = ((float)cx0 + 0.5f) * STEP, px1 = px0 + STEP;
  float py0 = ((float)cy0 + 0.5f) * STEP, py1 = py0 + STEP;
  float pz0 = ((float)cz0 + 0.5f) * STEP, pz1 = pz0 + STEP;

  int lz = max(Bz - 1, 0), hz = min(Bz + 1, BD - 1);
  int bb = b ? NBIN : 0;

  float acc[2][2][2][4];
#pragma unroll
  for (int i = 0; i < 2; ++i)
#pragma unroll
    for (int j = 0; j < 2; ++j)
#pragma unroll
      for (int k = 0; k < 2; ++k)
#pragma unroll
        for (int c = 0; c < 4; ++c) acc[i][j][k][c] = 0.f;

  int col = -1;
  int p = 0, e = 0;
  while (true) {
    // advance cursor to next non-empty column (per-lane)
    while (p >= e && col < 9) {
      ++col;
      if (col < 9) {
        // col -> (ox, oy) in { -1, 0, 1 }^2, ix-major to keep R6's order
        int ox = (col >= 6) ? 1 : ((col >= 3) ? 0 : -1);
        int oy = col - ((ox + 1) * 3) - 1;
        int ix = Bx + ox, iy = By + oy;
        if (((unsigned)ix < (unsigned)BD) & ((unsigned)iy < (unsigned)BD)) {
          int base = bb + (((ix << 6) + iy) << 6);
          p = starts[base + lz];
          e = starts[base + hz] + counts[base + hz];  // within-column end
        }
      }
    }
    if (__all(col >= 9)) break;
    if (col < 9) {
      float4 a = sA[p];
      float4 v = sB[p];
      ++p;
      float dx0 = a.x - px0, dx1 = a.x - px1;
      float dy0 = a.y - py0, dy1 = a.y - py1;
      float dz0 = a.z - pz0, dz1 = a.z - pz1;
      float dx2[2] = {dx0 * dx0, dx1 * dx1};
      float dy2[2] = {dy0 * dy0, dy1 * dy1};
      float dz2[2] = {dz0 * dz0, dz1 * dz1};
#pragma unroll
      for (int i = 0; i < 2; ++i) {
#pragma unroll
        for (int j = 0; j < 2; ++j) {
          float dxy = dx2[i] + dy2[j];
#pragma unroll
          for (int k = 0; k < 2; ++k) {
            float d2 = dxy + dz2[k];
            // branchless: compute spline always, mask with d2 < H2
            float q = sqrtf(d2) * INV_H;
            float om = 1.0f - q;
            float wh = 2.0f * om * om * om;
            float wl = fmaf(6.0f * q * q, q - 1.0f, 1.0f);
            float w = (q < 0.5f) ? wl : wh;
            w = (d2 < H2) ? w : 0.0f;
            acc[i][j][k][0] = fmaf(w, a.w, acc[i][j][k][0]);
            acc[i][j][k][1] = fmaf(w, v.x, acc[i][j][k][1]);
            acc[i][j][k][2] = fmaf(w, v.y, acc[i][j][k][2]);
            acc[i][j][k][3] = fmaf(w, v.z, acc[i][j][k][3]);
          }
        }
      }
    }
  }

#pragma unroll
  for (int i = 0; i < 2; ++i)
#pragma unroll
    for (int j = 0; j < 2; ++j)
#pragma unroll
      for (int k = 0; k < 2; ++k) {
        int cell = (((cx0 + i) * GY) + (cy0 + j)) * GZ + (cz0 + k);
        out[((size_t)b << 21) + cell] =
            make_float4(acc[i][j][k][0], acc[i][j][k][1],
                        acc[i][j][k][2], acc[i][j][k][3]);
      }
}

// ---------------- launch ----------------
static inline size_t align_up(size_t x, size_t a) { return (x + a - 1) & ~(a - 1); }

extern "C" void kernel_launch(void* const* d_in, const int* in_sizes, int n_in,
                              void* d_out, int out_size, void* d_ws, size_t ws_size,
                              hipStream_t stream) {
  const float* locs    = (const float*)d_in[0];   // (B,N,4) f32
  const float* data    = (const float*)d_in[1];   // (B,N,4) f32
  const float* density = (const float*)d_in[2];   // (B,N)   f32
  float* out = (float*)d_out;                      // (B,128,128,128,4) f32

  int nTotal = in_sizes[2];              // B*N = 200000
  int B      = out_size / (NC * 4);      // 2
  int nPart  = nTotal / B;               // 100000

  // workspace layout: [counts | totalCursor | starts | cursor | sA | sB]
  size_t o_counts = 0;
  size_t o_total  = sizeof(int) * NB_TOT;                       // 1 int
  size_t o_starts = align_up(o_total + sizeof(int), 256);
  size_t o_cursor = align_up(o_starts + sizeof(int) * NB_TOT, 256);
  size_t o_sA     = align_up(o_cursor + sizeof(int) * NB_TOT, 256);
  size_t o_sB     = align_up(o_sA + sizeof(float4) * (size_t)nTotal, 256);
  size_t need     = o_sB + sizeof(float4) * (size_t)nTotal;

  if (B != 2 || ws_size < need) {
    // fallback: proven scatter-atomic path
    int n4 = out_size / 4;
    int zblocks = min((n4 + 255) / 256, 2048);
    zero_kernel<<<zblocks, 256, 0, stream>>>(reinterpret_cast<float4*>(out), n4);
    dim3 grid((nTotal + 255) / 256, 5);
    splat_kernel<<<grid, 256, 0, stream>>>(
        reinterpret_cast<const float4*>(locs),
        reinterpret_cast<const float4*>(data), density, out, nTotal, nPart);
    return;
  }

  char* ws = (char*)d_ws;
  int* counts   = (int*)(ws + o_counts);
  int* totalCur = (int*)(ws + o_total);
  int* starts   = (int*)(ws + o_starts);
  int* cursor   = (int*)(ws + o_cursor);
  float4* sA    = (float4*)(ws + o_sA);
  float4* sB    = (float4*)(ws + o_sB);

  int pblocks = (nTotal + 255) / 256;

  // zero counts + totalCursor in one memset (capture-safe: async on stream)
  hipMemsetAsync(ws, 0, sizeof(int) * (NB_TOT + 1), stream);
  count_kernel<<<pblocks, 256, 0, stream>>>(
      reinterpret_cast<const float4*>(locs), counts, nTotal, nPart);
  scan_fused<<<NB_TOT / 1024, 256, 0, stream>>>(counts, starts, cursor, totalCur);
  scatter_kernel<<<pblocks, 256, 0, stream>>>(
      reinterpret_cast<const float4*>(locs),
      reinterpret_cast<const float4*>(data), density, cursor, sA, sB,
      nTotal, nPart);
  gather8f_kernel<<<(2 * NBIN) / 128, 128, 0, stream>>>(
      starts, counts, sA, sB, reinterpret_cast<float4*>(out));
}

// Round 11
// 164.770 us; speedup vs baseline: 1.2620x; 1.2620x over previous
//
#include <hip/hip_runtime.h>

// Particles2Grid: SPH cubic-spline splat, B=2, N=100000, C=4, grid 128^3.
// R4 scatter-atomics: 1403us. R5 bin+gather: 240us. R6 8-cells/thread: 177us
// (gather 84us, VALUBusy 92% -> VALU-issue-bound). R7 flattened cursor:
// REGRESSED (gather 113us — state machine killed unroll/ILP, instr count UP).
// R8: __sqrtf doesn't exist in HIP device code (compile fail). R9: same plan
// with __builtin_amdgcn_sqrtf (raw v_sqrt_f32, paid 8x per candidate) +
// interleaved sAB (32B txns) on the proven R6 gather structure. R10/R11:
// resubmit (R9/R10 never ran — GPU acquisition timeouts).

constexpr int GX = 128, GY = 128, GZ = 128;
constexpr int NC = GX * GY * GZ;            // 2^21
constexpr int BD = 64;                       // bins per dim (2 cells/bin)
constexpr int NBIN = BD * BD * BD;           // 262144 per batch
constexpr int NB_TOT = 2 * NBIN;             // 524288 (B = 2)
constexpr float STEP   = 0.1f;
constexpr float INV_H  = 5.0f;               // 1 / 0.2
constexpr float H2     = 0.04f;              // 0.2^2
constexpr float SIGMA  = 318.30988618379067f; // 8 / (pi h^3)

// ---------------- fallback path (proven correct in R4) ----------------
__global__ __launch_bounds__(256) void zero_kernel(float4* __restrict__ out, int n4) {
  int stride = gridDim.x * blockDim.x;
  for (int i = blockIdx.x * blockDim.x + threadIdx.x; i < n4; i += stride)
    out[i] = make_float4(0.f, 0.f, 0.f, 0.f);
}

__global__ __launch_bounds__(256) void splat_kernel(
    const float4* __restrict__ locs, const float4* __restrict__ data,
    const float* __restrict__ density, float* __restrict__ out,
    int nTotal, int nPart) {
  int pid = blockIdx.x * blockDim.x + threadIdx.x;
  if (pid >= nTotal) return;
  int ox = blockIdx.y;
  float4 loc = locs[pid];
  float scale = 1.0f / (loc.w * density[pid]);
  int bx = (int)floorf(loc.x / STEP);
  int by = (int)floorf(loc.y / STEP);
  int bz = (int)floorf(loc.z / STEP);
  int cx = bx + ox - 2;
  if ((unsigned)cx >= (unsigned)GX) return;
  float dx = ((float)cx + 0.5f) * STEP - loc.x;
  float dx2 = dx * dx;
  if (dx2 >= H2) return;
  float4 dat = data[pid];
  int b = (pid >= nPart) ? 1 : 0;
  float* outb = out + (size_t)b * NC * 4;
  for (int oy = 0; oy < 5; ++oy) {
    int cy = by + oy - 2;
    if ((unsigned)cy >= (unsigned)GY) continue;
    float dy = ((float)cy + 0.5f) * STEP - loc.y;
    float dxy2 = dx2 + dy * dy;
    if (dxy2 >= H2) continue;
    float* rowp = outb + (size_t)((cx * GY + cy) * GZ) * 4;
    for (int oz = 0; oz < 5; ++oz) {
      int cz = bz + oz - 2;
      if ((unsigned)cz >= (unsigned)GZ) continue;
      float dz = ((float)cz + 0.5f) * STEP - loc.z;
      float d2 = dxy2 + dz * dz;
      if (d2 >= H2) continue;
      float q = sqrtf(d2) * INV_H;
      float w = (q < 0.5f) ? (1.0f + 6.0f * q * q * (q - 1.0f))
                           : (2.0f * (1.0f - q) * (1.0f - q) * (1.0f - q));
      float coef = SIGMA * scale * w;
      float* cellp = rowp + cz * 4;
      unsafeAtomicAdd(cellp + 0, coef * dat.x);
      unsafeAtomicAdd(cellp + 1, coef * dat.y);
      unsafeAtomicAdd(cellp + 2, coef * dat.z);
      unsafeAtomicAdd(cellp + 3, coef * dat.w);
    }
  }
}

// ---------------- binning + gather path ----------------

__device__ __forceinline__ int particle_bin(float4 l, int isB1) {
  int bx = (int)floorf(l.x / STEP);
  int by = (int)floorf(l.y / STEP);
  int bz = (int)floorf(l.z / STEP);
  bx = min(max(bx, 0), GX - 1) >> 1;
  by = min(max(by, 0), GY - 1) >> 1;
  bz = min(max(bz, 0), GZ - 1) >> 1;
  return (isB1 ? NBIN : 0) + ((bx * BD) + by) * BD + bz;
}

__global__ __launch_bounds__(256) void count_kernel(
    const float4* __restrict__ locs, int* __restrict__ counts,
    int nTotal, int nPart) {
  int pid = blockIdx.x * blockDim.x + threadIdx.x;
  if (pid >= nTotal) return;
  int bin = particle_bin(locs[pid], pid >= nPart);
  atomicAdd(counts + bin, 1);
}

// Fused scan: per-block (1024-bin chunk) exclusive scan; chunk base reserved
// via atomicAdd on a global cursor (arrival order). Cross-chunk order is
// arbitrary, but gather only needs within-COLUMN contiguity (columns are
// 64-bin aligned; a 1024-bin chunk = 16 whole columns) and computes window
// ends as starts[last] + counts[last] — never reads across a chunk boundary.
__global__ __launch_bounds__(256) void scan_fused(
    const int* __restrict__ counts, int* __restrict__ starts,
    int* __restrict__ cursor, int* __restrict__ totalCursor) {
  __shared__ int sh[256];
  __shared__ int chunkBaseSh;
  int t = threadIdx.x, bid = blockIdx.x;
  int base = bid * 1024 + t * 4;
  int4 c = *reinterpret_cast<const int4*>(counts + base);
  int s = c.x + c.y + c.z + c.w;
  sh[t] = s;
  __syncthreads();
  for (int off = 1; off < 256; off <<= 1) {
    int x = (t >= off) ? sh[t - off] : 0;
    __syncthreads();
    sh[t] += x;
    __syncthreads();
  }
  int incl = sh[t];
  if (t == 255) chunkBaseSh = atomicAdd(totalCursor, incl);
  __syncthreads();
  int run = chunkBaseSh + incl - s;        // exclusive within chunk + base
  int4 o;
  o.x = run; run += c.x;
  o.y = run; run += c.y;
  o.z = run; run += c.z;
  o.w = run;
  *reinterpret_cast<int4*>(starts + base) = o;
  *reinterpret_cast<int4*>(cursor + base) = o;
}

// scatter: interleaved sAB — one 32B-contiguous pair per particle (one txn
// instead of two 16B stores into two different lines).
__global__ __launch_bounds__(256) void scatter_kernel(
    const float4* __restrict__ locs, const float4* __restrict__ data,
    const float* __restrict__ density, int* __restrict__ cursor,
    float4* __restrict__ sAB, int nTotal, int nPart) {
  int pid = blockIdx.x * blockDim.x + threadIdx.x;
  if (pid >= nTotal) return;
  float4 l = locs[pid];
  float4 d = data[pid];
  float s = SIGMA / (l.w * density[pid]);
  int bin = particle_bin(l, pid >= nPart);
  int idx = atomicAdd(cursor + bin, 1);
  sAB[2 * idx]     = make_float4(l.x, l.y, l.z, s * d.x);
  sAB[2 * idx + 1] = make_float4(s * d.y, s * d.z, s * d.w, 0.f);
}

// gather8: one thread per 2x2x2 cell block (R6 structure — proven 84us).
// Cells 2k,2k+1 share bin window [k-1,k+1]; per-axis distance squares are
// computed once per candidate and combined 8x. Raw v_sqrt_f32 via builtin.
__global__ __launch_bounds__(256) void gather8_kernel(
    const int* __restrict__ starts, const int* __restrict__ counts,
    const float4* __restrict__ sAB, float4* __restrict__ out) {
  int tid = blockIdx.x * blockDim.x + threadIdx.x;   // 2 * 64^3
  int b   = tid >> 18;
  int blk = tid & ((1 << 18) - 1);
  int Bz = blk & 63;
  int By = (blk >> 6) & 63;
  int Bx = blk >> 12;

  int cx0 = Bx << 1, cy0 = By << 1, cz0 = Bz << 1;
  float px0 = ((float)cx0 + 0.5f) * STEP, px1 = px0 + STEP;
  float py0 = ((float)cy0 + 0.5f) * STEP, py1 = py0 + STEP;
  float pz0 = ((float)cz0 + 0.5f) * STEP, pz1 = pz0 + STEP;

  int lx = max(Bx - 1, 0), hx = min(Bx + 1, BD - 1);
  int ly = max(By - 1, 0), hy = min(By + 1, BD - 1);
  int lz = max(Bz - 1, 0), hz = min(Bz + 1, BD - 1);
  int bb = b ? NBIN : 0;

  float acc[2][2][2][4];
#pragma unroll
  for (int i = 0; i < 2; ++i)
#pragma unroll
    for (int j = 0; j < 2; ++j)
#pragma unroll
      for (int k = 0; k < 2; ++k)
#pragma unroll
        for (int c = 0; c < 4; ++c) acc[i][j][k][c] = 0.f;

  for (int ix = lx; ix <= hx; ++ix) {
    for (int iy = ly; iy <= hy; ++iy) {
      int base = bb + (((ix << 6) + iy) << 6);
      int s = starts[base + lz];
      int e = starts[base + hz] + counts[base + hz];  // within-column end
      for (int p = s; p < e; ++p) {
        float4 a = sAB[2 * p];
        float4 v = sAB[2 * p + 1];
        float dx0 = a.x - px0, dx1 = a.x - px1;
        float dy0 = a.y - py0, dy1 = a.y - py1;
        float dz0 = a.z - pz0, dz1 = a.z - pz1;
        float dx2[2] = {dx0 * dx0, dx1 * dx1};
        float dy2[2] = {dy0 * dy0, dy1 * dy1};
        float dz2[2] = {dz0 * dz0, dz1 * dz1};
#pragma unroll
        for (int i = 0; i < 2; ++i) {
#pragma unroll
          for (int j = 0; j < 2; ++j) {
            float dxy = dx2[i] + dy2[j];
#pragma unroll
            for (int k = 0; k < 2; ++k) {
              float d2 = dxy + dz2[k];
              if (d2 < H2) {
                float q = __builtin_amdgcn_sqrtf(d2) * INV_H;  // v_sqrt_f32
                float om = 1.0f - q;
                float wh = 2.0f * om * om * om;
                float wl = fmaf(6.0f * q * q, q - 1.0f, 1.0f);
                float w = (q < 0.5f) ? wl : wh;
                acc[i][j][k][0] = fmaf(w, a.w, acc[i][j][k][0]);
                acc[i][j][k][1] = fmaf(w, v.x, acc[i][j][k][1]);
                acc[i][j][k][2] = fmaf(w, v.y, acc[i][j][k][2]);
                acc[i][j][k][3] = fmaf(w, v.z, acc[i][j][k][3]);
              }
            }
          }
        }
      }
    }
  }

#pragma unroll
  for (int i = 0; i < 2; ++i)
#pragma unroll
    for (int j = 0; j < 2; ++j)
#pragma unroll
      for (int k = 0; k < 2; ++k) {
        int cell = (((cx0 + i) * GY) + (cy0 + j)) * GZ + (cz0 + k);
        out[((size_t)b << 21) + cell] =
            make_float4(acc[i][j][k][0], acc[i][j][k][1],
                        acc[i][j][k][2], acc[i][j][k][3]);
      }
}

// ---------------- launch ----------------
static inline size_t align_up(size_t x, size_t a) { return (x + a - 1) & ~(a - 1); }

extern "C" void kernel_launch(void* const* d_in, const int* in_sizes, int n_in,
                              void* d_out, int out_size, void* d_ws, size_t ws_size,
                              hipStream_t stream) {
  const float* locs    = (const float*)d_in[0];   // (B,N,4) f32
  const float* data    = (const float*)d_in[1];   // (B,N,4) f32
  const float* density = (const float*)d_in[2];   // (B,N)   f32
  float* out = (float*)d_out;                      // (B,128,128,128,4) f32

  int nTotal = in_sizes[2];              // B*N = 200000
  int B      = out_size / (NC * 4);      // 2
  int nPart  = nTotal / B;               // 100000

  // workspace layout: [counts | totalCursor | starts | cursor | sAB]
  size_t o_counts = 0;
  size_t o_total  = sizeof(int) * NB_TOT;                       // 1 int
  size_t o_starts = align_up(o_total + sizeof(int), 256);
  size_t o_cursor = align_up(o_starts + sizeof(int) * NB_TOT, 256);
  size_t o_sAB    = align_up(o_cursor + sizeof(int) * NB_TOT, 256);
  size_t need     = o_sAB + sizeof(float4) * 2 * (size_t)nTotal;

  if (B != 2 || ws_size < need) {
    // fallback: proven scatter-atomic path
    int n4 = out_size / 4;
    int zblocks = min((n4 + 255) / 256, 2048);
    zero_kernel<<<zblocks, 256, 0, stream>>>(reinterpret_cast<float4*>(out), n4);
    dim3 grid((nTotal + 255) / 256, 5);
    splat_kernel<<<grid, 256, 0, stream>>>(
        reinterpret_cast<const float4*>(locs),
        reinterpret_cast<const float4*>(data), density, out, nTotal, nPart);
    return;
  }

  char* ws = (char*)d_ws;
  int* counts   = (int*)(ws + o_counts);
  int* totalCur = (int*)(ws + o_total);
  int* starts   = (int*)(ws + o_starts);
  int* cursor   = (int*)(ws + o_cursor);
  float4* sAB   = (float4*)(ws + o_sAB);

  int pblocks = (nTotal + 255) / 256;

  // zero counts + totalCursor in one memset (capture-safe: async on stream)
  (void)hipMemsetAsync(ws, 0, sizeof(int) * (NB_TOT + 1), stream);
  count_kernel<<<pblocks, 256, 0, stream>>>(
      reinterpret_cast<const float4*>(locs), counts, nTotal, nPart);
  scan_fused<<<NB_TOT / 1024, 256, 0, stream>>>(counts, starts, cursor, totalCur);
  scatter_kernel<<<pblocks, 256, 0, stream>>>(
      reinterpret_cast<const float4*>(locs),
      reinterpret_cast<const float4*>(data), density, cursor, sAB,
      nTotal, nPart);
  gather8_kernel<<<(2 * NBIN) / 256, 256, 0, stream>>>(
      starts, counts, sAB, reinterpret_cast<float4*>(out));
}